// Round 6
// baseline (771.478 us; speedup 1.0000x reference)
//
#include <hip/hip_runtime.h>
#include <stdint.h>

#define T_SEQ 500
#define D_IN  32
#define BDIM  512

using short8  = __attribute__((ext_vector_type(8))) short;  // 8 bf16
using float4_ = __attribute__((ext_vector_type(4))) float;  // MFMA C/D frag

#define MFMA16(a,b,c) __builtin_amdgcn_mfma_f32_16x16x32_bf16((a),(b),(c),0,0,0)
#define F4Z (float4_){0.f,0.f,0.f,0.f}

// ---------------- LDS geometry ----------------
// h: packed u32 (hi<<16|lo) [buf2][row16][68 u32]  (64 units + 4 pad -> 272B rows)
// x: packed u32 [slot2][row16][36 u32]             (32 k + 4 pad -> 144B rows)
#define H_ROW_U32  68
#define H_BUF_U32  (16*H_ROW_U32)          // 1088
#define X_ROW_U32  36
#define X_SLOT_U32 (16*X_ROW_U32)          // 576
#define X_BASE_U32 (2*H_BUF_U32)           // 2176
#define LDS_U32    (X_BASE_U32 + 2*X_SLOT_U32)   // 3328 u32 = 13312 B

// ---------------- workspace layout (bytes) — identical to r5 (proven) ----------------
#define WS_ENC   0                                // [kt3][w8][tl2][hl2][lane64] short8
#define WS_DEC0  (WS_ENC  + 3*8*2*2*64*16)        // 98304
#define WS_COMB  (WS_DEC0 + 2*8*2*2*64*16)        // 163840
#define WS_OUT   (WS_COMB + 2*8*2*2*64*16)        // 229376 : [kt2][tl2][hl2][lane64]
#define WS_BENC  (WS_OUT  + 2*2*2*64*16)          // 237568 : [w8][tl2][lane64] f32
#define WS_BDEC0 (WS_BENC  + 8*2*64*4)            // 241664
#define WS_BCOMB (WS_BDEC0 + 8*2*64*4)            // 245760
#define WS_BOUT  (WS_BCOMB + 8*2*64*4)            // 249856 : [tl2][lane64] f32

// gate scale folded into weights: i,f,o -> -log2(e); g -> +2*log2(e)
#define S_SIG  (-1.4426950408889634f)
#define S_TANH ( 2.8853900817779268f)

__device__ __forceinline__ void split_bf16(float v, unsigned short &hi, unsigned short &lo) {
    unsigned int b = __float_as_uint(v);
    hi = (unsigned short)(b >> 16);
    float vh = __uint_as_float(b & 0xFFFF0000u);
    lo = (unsigned short)(__float_as_uint(v - vh) >> 16);
}

// LDS-only barrier (no vmcnt drain, no sched pins)
__device__ __forceinline__ void lds_barrier() {
    asm volatile("s_waitcnt lgkmcnt(0)\n\ts_barrier" ::: "memory");
}

// lane^8 exchange within each 16-lane row via DPP row_ror:8 (VALU, no LDS pipe)
__device__ __forceinline__ float dpp_x8(float v) {
    return __int_as_float(__builtin_amdgcn_mov_dpp(__float_as_int(v), 0x128, 0xf, 0xf, true));
}

// ==================== prep kernel (r5 structure; NEW intra-frag k-map) ====================
// compact frag element j of lane (rg,lcol):  k = kt*32 + (j>>2)*16 + rg*4 + (j&3)
// (lane-local expandable to the K'-interleaved form used by the main kernel)
__global__ void __launch_bounds__(512)
prep_kernel(const float* __restrict__ Wih_e, const float* __restrict__ Whh_e,
            const float* __restrict__ b_e,
            const float* __restrict__ Wih_d, const float* __restrict__ Whh_d,
            const float* __restrict__ b_d,
            const float* __restrict__ Wout, const float* __restrict__ bout,
            char* __restrict__ ws)
{
    const int tid  = blockIdx.x * blockDim.x + threadIdx.x;
    const int nthr = gridDim.x * blockDim.x;

    // encoder gate fragments: slots (kt3, w8, tl2, lane64)
    for (int s = tid; s < 3*8*2*64; s += nthr) {
        const int lane = s & 63, tl = (s >> 6) & 1, w = (s >> 7) & 7, kt = s >> 10;
        const int c = lane & 15, rg = lane >> 4;
        const int gate = tl*2 + (c >> 3);
        const int unit = w*8 + (c & 7);
        const int n = gate*64 + unit;
        const float sc = (gate == 2) ? S_TANH : S_SIG;
        short8 hi8, lo8;
        #pragma unroll
        for (int j = 0; j < 8; ++j) {
            const int k = kt*32 + ((j>>2)<<4) + (rg<<2) + (j&3);
            const float wv = sc * ((k < 32) ? Wih_e[n*D_IN + k] : Whh_e[n*64 + k - 32]);
            unsigned short h_, l_; split_bf16(wv, h_, l_);
            hi8[j] = (short)h_; lo8[j] = (short)l_;
        }
        const size_t base = (size_t)((((kt*8+w)*2+tl)*2+0)*64 + lane) * 16;
        *(short8*)(ws + WS_ENC + base)           = hi8;
        *(short8*)(ws + WS_ENC + base + 64*16)   = lo8;
    }

    // decoder step-0 (Whh_d) and combined (Whh_d + Wih_d@Wout): slots (kt2, w8, tl2, lane64)
    for (int s = tid; s < 2*8*2*64; s += nthr) {
        const int lane = s & 63, tl = (s >> 6) & 1, w = (s >> 7) & 7, kt = s >> 10;
        const int c = lane & 15, rg = lane >> 4;
        const int gate = tl*2 + (c >> 3);
        const int unit = w*8 + (c & 7);
        const int n = gate*64 + unit;
        const float sc = (gate == 2) ? S_TANH : S_SIG;
        short8 h0v, l0v, hcv, lcv;
        #pragma unroll
        for (int j = 0; j < 8; ++j) {
            const int k = kt*32 + ((j>>2)<<4) + (rg<<2) + (j&3);
            const float w0 = Whh_d[n*64 + k];
            float a = w0;
            for (int d = 0; d < 32; ++d) a += Wih_d[n*D_IN + d] * Wout[d*64 + k];
            unsigned short h_, l_;
            split_bf16(sc * w0, h_, l_); h0v[j] = (short)h_; l0v[j] = (short)l_;
            split_bf16(sc * a,  h_, l_); hcv[j] = (short)h_; lcv[j] = (short)l_;
        }
        const size_t base = (size_t)((((kt*8+w)*2+tl)*2+0)*64 + lane) * 16;
        *(short8*)(ws + WS_DEC0 + base)         = h0v;
        *(short8*)(ws + WS_DEC0 + base + 64*16) = l0v;
        *(short8*)(ws + WS_COMB + base)         = hcv;
        *(short8*)(ws + WS_COMB + base + 64*16) = lcv;
    }

    // Wout fragments: slots (kt2, tl2, lane64); col = tl*16 + (lane&15)
    for (int s = tid; s < 2*2*64; s += nthr) {
        const int lane = s & 63, tl = (s >> 6) & 1, kt = s >> 7;
        const int rg = lane >> 4;
        const int ocol = tl*16 + (lane & 15);
        short8 hi8, lo8;
        #pragma unroll
        for (int j = 0; j < 8; ++j) {
            const int k = kt*32 + ((j>>2)<<4) + (rg<<2) + (j&3);
            unsigned short h_, l_; split_bf16(Wout[ocol*64 + k], h_, l_);
            hi8[j] = (short)h_; lo8[j] = (short)l_;
        }
        const size_t base = (size_t)(((kt*2+tl)*2+0)*64 + lane) * 16;
        *(short8*)(ws + WS_OUT + base)         = hi8;
        *(short8*)(ws + WS_OUT + base + 64*16) = lo8;
    }

    // biases: slots (w8, tl2, lane64)
    for (int s = tid; s < 8*2*64; s += nthr) {
        const int lane = s & 63, tl = (s >> 6) & 1, w = s >> 7;
        const int c = lane & 15;
        const int gate = tl*2 + (c >> 3);
        const int unit = w*8 + (c & 7);
        const int n = gate*64 + unit;
        const float sc = (gate == 2) ? S_TANH : S_SIG;
        float a = b_d[n];
        for (int d = 0; d < 32; ++d) a += Wih_d[n*D_IN + d] * bout[d];
        ((float*)(ws + WS_BENC))[s]  = sc * b_e[n];
        ((float*)(ws + WS_BDEC0))[s] = sc * b_d[n];
        ((float*)(ws + WS_BCOMB))[s] = sc * a;
    }
    for (int s = tid; s < 2*64; s += nthr)
        ((float*)(ws + WS_BOUT))[s] = bout[(s >> 6)*16 + (s & 15)];
}

// ---- compact->interleaved expansion helpers (one-time per phase) ----
__device__ __forceinline__ short8 mk8(uint32_t a, uint32_t b, uint32_t c, uint32_t d) {
    union { uint32_t u[4]; short8 s; } t; t.u[0]=a; t.u[1]=b; t.u[2]=c; t.u[3]=d; return t.s;
}
__device__ __forceinline__ uint32_t dupL(uint32_t x) { return (x & 0xffffu) | (x << 16); }
__device__ __forceinline__ uint32_t dupH(uint32_t x) { return (x >> 16) | (x & 0xffff0000u); }

// B1 pair from compact-hi: every k' gets w_hi[k'>>1]
__device__ __forceinline__ void expand_hi(short8 c, short8 &o0, short8 &o1) {
    union { short8 s; uint32_t u[4]; } t; t.s = c;
    o0 = mk8(dupL(t.u[0]), dupH(t.u[0]), dupL(t.u[1]), dupH(t.u[1]));
    o1 = mk8(dupL(t.u[2]), dupH(t.u[2]), dupL(t.u[3]), dupH(t.u[3]));
}
// B2 pair from compact-lo: k' even -> 0 (multiplies lo), k' odd -> w_lo (multiplies hi)
__device__ __forceinline__ void expand_lo(short8 c, short8 &o0, short8 &o1) {
    union { short8 s; uint32_t u[4]; } t; t.s = c;
    o0 = mk8(t.u[0] << 16, t.u[0] & 0xffff0000u, t.u[1] << 16, t.u[1] & 0xffff0000u);
    o1 = mk8(t.u[2] << 16, t.u[2] & 0xffff0000u, t.u[3] << 16, t.u[3] & 0xffff0000u);
}

// ==================== main kernel ====================
extern "C" __global__ void __launch_bounds__(BDIM, 2)
seq2seq_main(const float* __restrict__ x, const char* __restrict__ ws,
             float* __restrict__ out)
{
    __shared__ uint32_t lds[LDS_U32];
    char* ldsb = (char*)lds;

    const int tid  = threadIdx.x;
    const int w    = tid >> 6;
    const int lane = tid & 63;
    const int rg   = lane >> 4;
    const int lcol = lane & 15;
    const int sel  = lcol >> 3;            // 0: owns i/g rows rg*4+{0,1}; 1: owns f/o rows rg*4+{2,3}
    const int uu   = lcol & 7;             // unit-within-wave
    const int row0 = blockIdx.x * 16;
    const int xrw = tid >> 5, xk = tid & 31;

    // interleaved weight fragments (expanded in registers, loaded once per phase)
    short8 B1[6][2], B2[6][2];
    float  bias[2];

    // phase loads: nkt compact chunks -> 2*nkt interleaved chunks (compile-time variants)
    auto ld_compact = [&](size_t wsoff, int kt, int tl, short8 &ch, short8 &cl) {
        const size_t base = (size_t)((((kt*8+w)*2+tl)*2+0)*64 + lane) * 16;
        ch = *(const short8*)(ws + wsoff + base);
        cl = *(const short8*)(ws + wsoff + base + 64*16);
    };
    auto load3 = [&](size_t wsoff, size_t boff) {      // encoder: kt 0..2 -> B1/B2[0..5]
        #pragma unroll
        for (int kt = 0; kt < 3; ++kt)
            #pragma unroll
            for (int tl = 0; tl < 2; ++tl) {
                short8 ch, cl; ld_compact(wsoff, kt, tl, ch, cl);
                expand_hi(ch, B1[2*kt][tl], B1[2*kt+1][tl]);
                expand_lo(cl, B2[2*kt][tl], B2[2*kt+1][tl]);
            }
        #pragma unroll
        for (int tl = 0; tl < 2; ++tl)
            bias[tl] = ((const float*)(ws + boff))[(w*2+tl)*64 + lane];
    };
    auto load2 = [&](size_t wsoff, size_t boff) {      // decoder: kt 0..1 -> B1/B2[0..3]
        #pragma unroll
        for (int kt = 0; kt < 2; ++kt)
            #pragma unroll
            for (int tl = 0; tl < 2; ++tl) {
                short8 ch, cl; ld_compact(wsoff, kt, tl, ch, cl);
                expand_hi(ch, B1[2*kt][tl], B1[2*kt+1][tl]);
                expand_lo(cl, B2[2*kt][tl], B2[2*kt+1][tl]);
            }
        #pragma unroll
        for (int tl = 0; tl < 2; ++tl)
            bias[tl] = ((const float*)(ws + boff))[(w*2+tl)*64 + lane];
    };

    float c2[2] = {0.f, 0.f};

    // zero h buf0
    for (int i = tid; i < H_BUF_U32; i += BDIM) lds[i] = 0u;

    // stage x[0] (packed), prefetch x[1]
    {
        const float v0 = x[((size_t)(row0 + xrw)*T_SEQ + 0)*D_IN + xk];
        unsigned short h_, l_; split_bf16(v0, h_, l_);
        lds[X_BASE_U32 + 0*X_SLOT_U32 + xrw*X_ROW_U32 + xk] = ((uint32_t)h_ << 16) | l_;
    }
    float xreg = x[((size_t)(row0 + xrw)*T_SEQ + 1)*D_IN + xk];
    lds_barrier();

    // pointwise: dpp gate-exchange + LSTM nonlinearities + packed h write (2 rows/lane)
    auto pw = [&](float4_ a0, float4_ a1, int nxt) {
        float sw0[4], sw1[4];
        #pragma unroll
        for (int r = 0; r < 4; ++r) { sw0[r] = dpp_x8(a0[r]); sw1[r] = dpp_x8(a1[r]); }
        #pragma unroll
        for (int si = 0; si < 2; ++si) {
            const float ip = sel ? sw0[2+si] : a0[si];
            const float fp = sel ? a0[2+si]  : sw0[si];
            const float gp = sel ? sw1[2+si] : a1[si];
            const float op = sel ? a1[2+si]  : sw1[si];
            const float ia = __builtin_amdgcn_rcpf(1.0f + __builtin_amdgcn_exp2f(ip));
            const float fa = __builtin_amdgcn_rcpf(1.0f + __builtin_amdgcn_exp2f(fp));
            const float ga = __builtin_fmaf(-2.0f,
                              __builtin_amdgcn_rcpf(1.0f + __builtin_amdgcn_exp2f(gp)), 1.0f);
            const float oa = __builtin_amdgcn_rcpf(1.0f + __builtin_amdgcn_exp2f(op));
            const float cv = __builtin_fmaf(fa, c2[si], ia * ga);
            c2[si] = cv;
            const float tt = __builtin_amdgcn_exp2f(cv * -2.8853900817779268f);
            const float hv = __builtin_fmaf(2.0f * oa,
                              __builtin_amdgcn_rcpf(1.0f + tt), -oa);
            unsigned short hh_, ll_; split_bf16(hv, hh_, ll_);
            const int row = rg*4 + sel*2 + si;
            lds[nxt*H_BUF_U32 + row*H_ROW_U32 + w*8 + uu] = ((uint32_t)hh_ << 16) | ll_;
        }
    };

    // A' fragment reads
    auto ldh = [&](int buf, int kt) {   // h chunks kt' 0..3
        return *(const short8*)(ldsb + buf*(H_BUF_U32*4) + lcol*(H_ROW_U32*4) + kt*64 + rg*16);
    };
    auto ldx = [&](int slot, int kt) {  // x chunks kt' 0..1
        return *(const short8*)(ldsb + X_BASE_U32*4 + slot*(X_SLOT_U32*4) + lcol*(X_ROW_U32*4) + kt*64 + rg*16);
    };

    // ---------------- encoder: 500 steps ----------------
    load3(WS_ENC, WS_BENC);
    auto enc_step = [&](int CUR, int t) {
        const int NXT = CUR ^ 1;
        const short8 a0 = ldx(CUR, 0), a1 = ldx(CUR, 1);
        const short8 a2 = ldh(CUR, 0), a3 = ldh(CUR, 1);
        const short8 a4 = ldh(CUR, 2), a5 = ldh(CUR, 3);

        const float xold = xreg;
        xreg = (t + 2 < T_SEQ) ? x[((size_t)(row0 + xrw)*T_SEQ + (t+2))*D_IN + xk] : 0.f;
        if (t + 1 < T_SEQ) {
            unsigned short h_, l_; split_bf16(xold, h_, l_);
            lds[X_BASE_U32 + NXT*X_SLOT_U32 + xrw*X_ROW_U32 + xk] = ((uint32_t)h_ << 16) | l_;
        }

        float4_ acc[2];
        #pragma unroll
        for (int tl = 0; tl < 2; ++tl) {
            float4_ cA = {bias[tl], bias[tl], bias[tl], bias[tl]};
            cA = MFMA16(a0, B1[0][tl], cA);
            cA = MFMA16(a1, B1[1][tl], cA);
            cA = MFMA16(a2, B1[2][tl], cA);
            float4_ cB = MFMA16(a3, B1[3][tl], F4Z);
            cB = MFMA16(a4, B1[4][tl], cB);
            cB = MFMA16(a5, B1[5][tl], cB);
            float4_ cC = MFMA16(a0, B2[0][tl], F4Z);
            cC = MFMA16(a1, B2[1][tl], cC);
            cC = MFMA16(a2, B2[2][tl], cC);
            float4_ cD = MFMA16(a3, B2[3][tl], F4Z);
            cD = MFMA16(a4, B2[4][tl], cD);
            cD = MFMA16(a5, B2[5][tl], cD);
            acc[tl] = (cA + cB) + (cC + cD);
        }
        pw(acc[0], acc[1], NXT);
        lds_barrier();
    };

    int t = 0;
    for (int it = 0; it < 250; ++it) { enc_step(0, t); ++t; enc_step(1, t); ++t; }
    // h_enc in buf 0

    // ---------------- decoder step 0 (input = zeros; Whh_d) ----------------
    load2(WS_DEC0, WS_BDEC0);
    {
        const short8 a0 = ldh(0, 0), a1 = ldh(0, 1), a2 = ldh(0, 2), a3 = ldh(0, 3);
        float4_ acc[2];
        #pragma unroll
        for (int tl = 0; tl < 2; ++tl) {
            float4_ cA = {bias[tl], bias[tl], bias[tl], bias[tl]};
            cA = MFMA16(a0, B1[0][tl], cA);
            cA = MFMA16(a1, B1[1][tl], cA);
            float4_ cB = MFMA16(a2, B1[2][tl], F4Z);
            cB = MFMA16(a3, B1[3][tl], cB);
            float4_ cC = MFMA16(a0, B2[0][tl], F4Z);
            cC = MFMA16(a1, B2[1][tl], cC);
            float4_ cD = MFMA16(a2, B2[2][tl], F4Z);
            cD = MFMA16(a3, B2[3][tl], cD);
            acc[tl] = (cA + cB) + (cC + cD);
        }
        pw(acc[0], acc[1], 1);
        lds_barrier();
    }

    // ---------------- decoder steps 1..499 (Wcomb; out as side-effect) ----------------
    load2(WS_COMB, WS_BCOMB);

    const bool ow  = (w == 0) || (w == 5);   // out-waves on different SIMDs
    const int  tlo = (w == 0) ? 0 : 1;
    const int  ocol = tlo*16 + lcol;
    short8 B1o[4] = {}, B2o[4] = {};
    float  bo = 0.f;
    if (ow) {
        #pragma unroll
        for (int kt = 0; kt < 2; ++kt) {
            const size_t base = (size_t)(((kt*2+tlo)*2+0)*64 + lane) * 16;
            short8 ch = *(const short8*)(ws + WS_OUT + base);
            short8 cl = *(const short8*)(ws + WS_OUT + base + 64*16);
            expand_hi(ch, B1o[2*kt], B1o[2*kt+1]);
            expand_lo(cl, B2o[2*kt], B2o[2*kt+1]);
        }
        bo = ((const float*)(ws + WS_BOUT))[tlo*64 + lane];
    }

    auto dec_step = [&](int CUR, int s) {
        const short8 a0 = ldh(CUR, 0), a1 = ldh(CUR, 1), a2 = ldh(CUR, 2), a3 = ldh(CUR, 3);
        float4_ acc[2];
        #pragma unroll
        for (int tl = 0; tl < 2; ++tl) {
            float4_ cA = {bias[tl], bias[tl], bias[tl], bias[tl]};
            cA = MFMA16(a0, B1[0][tl], cA);
            cA = MFMA16(a1, B1[1][tl], cA);
            float4_ cB = MFMA16(a2, B1[2][tl], F4Z);
            cB = MFMA16(a3, B1[3][tl], cB);
            float4_ cC = MFMA16(a0, B2[0][tl], F4Z);
            cC = MFMA16(a1, B2[1][tl], cC);
            float4_ cD = MFMA16(a2, B2[2][tl], F4Z);
            cD = MFMA16(a3, B2[3][tl], cD);
            acc[tl] = (cA + cB) + (cC + cD);
        }
        if (ow) {   // out_{s-1} = h_s @ Wout^T + bout (stores stay in flight across barrier)
            float4_ oA = {bo, bo, bo, bo};
            oA = MFMA16(a0, B1o[0], oA);
            oA = MFMA16(a1, B1o[1], oA);
            float4_ oB = MFMA16(a2, B1o[2], F4Z);
            oB = MFMA16(a3, B1o[3], oB);
            float4_ oC = MFMA16(a0, B2o[0], F4Z);
            oC = MFMA16(a1, B2o[1], oC);
            oC = MFMA16(a2, B2o[2], oC);
            oC = MFMA16(a3, B2o[3], oC);
            const float4_ ov = (oA + oB) + oC;
            #pragma unroll
            for (int r = 0; r < 4; ++r)
                out[((size_t)(row0 + rg*4 + r)*T_SEQ + (s-1))*D_IN + ocol] = ov[r];
        }
        pw(acc[0], acc[1], CUR ^ 1);
        lds_barrier();
    };

    int s = 1;
    for (int it = 0; it < 249; ++it) { dec_step(1, s); ++s; dec_step(0, s); ++s; }
    dec_step(1, s);   // s = 499; writes h_500 into buf 0

    // tail: out_499 = h_500 @ Wout^T + bout
    if (ow) {
        const short8 a0 = ldh(0, 0), a1 = ldh(0, 1), a2 = ldh(0, 2), a3 = ldh(0, 3);
        float4_ oA = {bo, bo, bo, bo};
        oA = MFMA16(a0, B1o[0], oA);
        oA = MFMA16(a1, B1o[1], oA);
        float4_ oB = MFMA16(a2, B1o[2], F4Z);
        oB = MFMA16(a3, B1o[3], oB);
        float4_ oC = MFMA16(a0, B2o[0], F4Z);
        oC = MFMA16(a1, B2o[1], oC);
        oC = MFMA16(a2, B2o[2], oC);
        oC = MFMA16(a3, B2o[3], oC);
        const float4_ ov = (oA + oB) + oC;
        #pragma unroll
        for (int r = 0; r < 4; ++r)
            out[((size_t)(row0 + rg*4 + r)*T_SEQ + (T_SEQ-1))*D_IN + ocol] = ov[r];
    }
}

extern "C" void kernel_launch(void* const* d_in, const int* in_sizes, int n_in,
                              void* d_out, int out_size, void* d_ws, size_t ws_size,
                              hipStream_t stream) {
    (void)n_in; (void)ws_size; (void)out_size;
    const float* x     = (const float*)d_in[0];
    const float* Wih_e = (const float*)d_in[1];
    const float* Whh_e = (const float*)d_in[2];
    const float* b_e   = (const float*)d_in[3];
    const float* Wih_d = (const float*)d_in[4];
    const float* Whh_d = (const float*)d_in[5];
    const float* b_d   = (const float*)d_in[6];
    const float* Wout  = (const float*)d_in[7];
    const float* bout  = (const float*)d_in[8];
    float* out = (float*)d_out;

    const int B = in_sizes[0] / (T_SEQ * D_IN);   // 4096

    hipLaunchKernelGGL(prep_kernel, dim3(8), dim3(512), 0, stream,
                       Wih_e, Whh_e, b_e, Wih_d, Whh_d, b_d, Wout, bout, (char*)d_ws);
    hipLaunchKernelGGL(seq2seq_main, dim3(B / 16), dim3(BDIM), 0, stream,
                       x, (const char*)d_ws, out);
}

// Round 7
// 576.425 us; speedup vs baseline: 1.3384x; 1.3384x over previous
//
#include <hip/hip_runtime.h>
#include <stdint.h>

#define T_SEQ 500
#define D_IN  32
#define BDIM  512

using short8  = __attribute__((ext_vector_type(8))) short;     // 8 bf16
using half8   = __attribute__((ext_vector_type(8))) _Float16;  // 8 fp16
using float4_ = __attribute__((ext_vector_type(4))) float;     // MFMA C/D frag

#define MFMAB(a,b,c) __builtin_amdgcn_mfma_f32_16x16x32_bf16((a),(b),(c),0,0,0)
#define MFMAH(a,b,c) __builtin_amdgcn_mfma_f32_16x16x32_f16((a),(b),(c),0,0,0)
#define F4Z (float4_){0.f,0.f,0.f,0.f}

// ---------------- LDS geometry: 272B frag blocks (16 rows x 16B + 16B pad) ----------------
#define BLK 272
#define ENC_H(buf,kt,g)    ((((buf)*2+(kt))*4+(g))*BLK)                    // blocks 0..15
#define ENC_X(slot,g)      (16*BLK + ((slot)*4+(g))*BLK)                   // blocks 16..23
#define DEC_H(buf,hl,kt,g) (24*BLK + ((((((buf)*2+(hl))*2+(kt))*4)+(g))*BLK)) // blocks 24..55
#define LDS_BYTES (56*BLK)   // 15232 B

// ---------------- workspace layout (bytes) ----------------
#define WS_ENC   0                                // [kt3][w8][tl2][hl2][lane64] x 16B (fp16 hi/lo)
#define WS_DEC0  (WS_ENC  + 3*8*2*2*64*16)        // 98304  (bf16 hi/lo)
#define WS_COMB  (WS_DEC0 + 2*8*2*2*64*16)        // 163840 (bf16 hi/lo)
#define WS_OUT   (WS_COMB + 2*8*2*2*64*16)        // 229376 : [kt2][tl2][hl2][lane64] (bf16)
#define WS_BENC  (WS_OUT  + 2*2*2*64*16)          // 237568 : [w8][tl2][lane64] f32
#define WS_BDEC0 (WS_BENC  + 8*2*64*4)            // 241664
#define WS_BCOMB (WS_BDEC0 + 8*2*64*4)            // 245760
#define WS_BOUT  (WS_BCOMB + 8*2*64*4)            // 249856 : [tl2][lane64] f32

// gate scale folded into weights: i,f,o -> -log2(e); g -> +2*log2(e)
#define S_SIG  (-1.4426950408889634f)
#define S_TANH ( 2.8853900817779268f)

__device__ __forceinline__ void split_bf16(float v, unsigned short &hi, unsigned short &lo) {
    unsigned int b = __float_as_uint(v);
    hi = (unsigned short)(b >> 16);
    float vh = __uint_as_float(b & 0xFFFF0000u);
    lo = (unsigned short)(__float_as_uint(v - vh) >> 16);
}
__device__ __forceinline__ void split_f16(float v, unsigned short &hi, unsigned short &lo) {
    _Float16 h = (_Float16)v;
    _Float16 l = (_Float16)(v - (float)h);
    union { _Float16 f; unsigned short u; } a, b;
    a.f = h; b.f = l; hi = a.u; lo = b.u;
}
__device__ __forceinline__ unsigned short f16_bits(float v) {
    union { _Float16 f; unsigned short u; } t; t.f = (_Float16)v; return t.u;
}

// LDS-only barrier (no vmcnt drain; out-stores & x-loads stay in flight)
__device__ __forceinline__ void lds_barrier() {
    asm volatile("s_waitcnt lgkmcnt(0)\n\ts_barrier" ::: "memory");
}
// lane^8 exchange within each 16-lane row (row_ror:8) — verified r6
__device__ __forceinline__ float dpp_x8(float v) {
    return __int_as_float(__builtin_amdgcn_mov_dpp(__float_as_int(v), 0x128, 0xf, 0xf, true));
}

// fused-rcp LSTM pointwise: ip,fp,op pre-scaled by -log2e; gp by +2log2e
__device__ __forceinline__ float lstm_h(float ip, float fp, float gp, float op, float &cc) {
    const float ei = __builtin_amdgcn_exp2f(ip);
    const float ef = __builtin_amdgcn_exp2f(fp);
    const float eg = __builtin_amdgcn_exp2f(gp);
    const float eo = __builtin_amdgcn_exp2f(op);
    const float pig = (eg - 1.0f) * __builtin_amdgcn_rcpf((1.0f + ei) * (1.0f + eg)); // sig(i)*tanh(g)
    const float fa  = __builtin_amdgcn_rcpf(1.0f + ef);                                // sig(f)
    cc = __builtin_fmaf(fa, cc, pig);
    const float ec = __builtin_amdgcn_exp2f(cc * -2.8853900817779268f);                // e^{-2c}
    return (1.0f - ec) * __builtin_amdgcn_rcpf((1.0f + eo) * (1.0f + ec));             // sig(o)*tanh(c)
}

// ==================== prep kernel ====================
// col map (wave w, tile tl, col c): gate = tl*2 + (c>>3), unit = w*8 + (c&7)
// frag element j of lane (rg=lane>>4): k = kt*32 + rg*8 + j
__global__ void __launch_bounds__(512)
prep_kernel(const float* __restrict__ Wih_e, const float* __restrict__ Whh_e,
            const float* __restrict__ b_e,
            const float* __restrict__ Wih_d, const float* __restrict__ Whh_d,
            const float* __restrict__ b_d,
            const float* __restrict__ Wout, const float* __restrict__ bout,
            char* __restrict__ ws)
{
    const int tid  = blockIdx.x * blockDim.x + threadIdx.x;
    const int nthr = gridDim.x * blockDim.x;

    // encoder fragments (fp16 hi/lo): slots (kt3, w8, tl2, lane64)
    for (int s = tid; s < 3*8*2*64; s += nthr) {
        const int lane = s & 63, tl = (s >> 6) & 1, w = (s >> 7) & 7, kt = s >> 10;
        const int c = lane & 15, rg = lane >> 4;
        const int gate = tl*2 + (c >> 3);
        const int unit = w*8 + (c & 7);
        const int n = gate*64 + unit;
        const float sc = (gate == 2) ? S_TANH : S_SIG;
        short8 hi8, lo8;
        #pragma unroll
        for (int j = 0; j < 8; ++j) {
            const int k = kt*32 + rg*8 + j;
            const float wv = sc * ((k < 32) ? Wih_e[n*D_IN + k] : Whh_e[n*64 + k - 32]);
            unsigned short h_, l_; split_f16(wv, h_, l_);
            hi8[j] = (short)h_; lo8[j] = (short)l_;
        }
        const size_t base = (size_t)((((kt*8+w)*2+tl)*2+0)*64 + lane) * 16;
        *(short8*)(ws + WS_ENC + base)           = hi8;
        *(short8*)(ws + WS_ENC + base + 64*16)   = lo8;
    }

    // decoder step-0 (Whh_d) and combined (Whh_d + Wih_d@Wout), bf16 hi/lo: (kt2, w8, tl2, lane64)
    for (int s = tid; s < 2*8*2*64; s += nthr) {
        const int lane = s & 63, tl = (s >> 6) & 1, w = (s >> 7) & 7, kt = s >> 10;
        const int c = lane & 15, rg = lane >> 4;
        const int gate = tl*2 + (c >> 3);
        const int unit = w*8 + (c & 7);
        const int n = gate*64 + unit;
        const float sc = (gate == 2) ? S_TANH : S_SIG;
        short8 h0v, l0v, hcv, lcv;
        #pragma unroll
        for (int j = 0; j < 8; ++j) {
            const int k = kt*32 + rg*8 + j;
            const float w0 = Whh_d[n*64 + k];
            float a = w0;
            for (int d = 0; d < 32; ++d) a += Wih_d[n*D_IN + d] * Wout[d*64 + k];
            unsigned short h_, l_;
            split_bf16(sc * w0, h_, l_); h0v[j] = (short)h_; l0v[j] = (short)l_;
            split_bf16(sc * a,  h_, l_); hcv[j] = (short)h_; lcv[j] = (short)l_;
        }
        const size_t base = (size_t)((((kt*8+w)*2+tl)*2+0)*64 + lane) * 16;
        *(short8*)(ws + WS_DEC0 + base)         = h0v;
        *(short8*)(ws + WS_DEC0 + base + 64*16) = l0v;
        *(short8*)(ws + WS_COMB + base)         = hcv;
        *(short8*)(ws + WS_COMB + base + 64*16) = lcv;
    }

    // Wout fragments (bf16): (kt2, tl2, lane64); col = tl*16 + (lane&15)
    for (int s = tid; s < 2*2*64; s += nthr) {
        const int lane = s & 63, tl = (s >> 6) & 1, kt = s >> 7;
        const int rg = lane >> 4;
        const int ocol = tl*16 + (lane & 15);
        short8 hi8, lo8;
        #pragma unroll
        for (int j = 0; j < 8; ++j) {
            const int k = kt*32 + rg*8 + j;
            unsigned short h_, l_; split_bf16(Wout[ocol*64 + k], h_, l_);
            hi8[j] = (short)h_; lo8[j] = (short)l_;
        }
        const size_t base = (size_t)(((kt*2+tl)*2+0)*64 + lane) * 16;
        *(short8*)(ws + WS_OUT + base)         = hi8;
        *(short8*)(ws + WS_OUT + base + 64*16) = lo8;
    }

    // biases: (w8, tl2, lane64)
    for (int s = tid; s < 8*2*64; s += nthr) {
        const int lane = s & 63, tl = (s >> 6) & 1, w = s >> 7;
        const int c = lane & 15;
        const int gate = tl*2 + (c >> 3);
        const int unit = w*8 + (c & 7);
        const int n = gate*64 + unit;
        const float sc = (gate == 2) ? S_TANH : S_SIG;
        float a = b_d[n];
        for (int d = 0; d < 32; ++d) a += Wih_d[n*D_IN + d] * bout[d];
        ((float*)(ws + WS_BENC))[s]  = sc * b_e[n];
        ((float*)(ws + WS_BDEC0))[s] = sc * b_d[n];
        ((float*)(ws + WS_BCOMB))[s] = sc * a;
    }
    for (int s = tid; s < 2*64; s += nthr)
        ((float*)(ws + WS_BOUT))[s] = bout[(s >> 6)*16 + (s & 15)];
}

// ==================== main kernel ====================
extern "C" __global__ void __launch_bounds__(BDIM, 2)
seq2seq_main(const float* __restrict__ x, const char* __restrict__ ws,
             float* __restrict__ out)
{
    __shared__ __align__(16) char lds[LDS_BYTES];

    const int tid  = threadIdx.x;
    const int w    = tid >> 6;
    const int lane = tid & 63;
    const int rg   = lane >> 4;
    const int lcol = lane & 15;
    const int sel  = lcol >> 3;
    const int row0 = blockIdx.x * 16;

    const int KT_H = w >> 2, G_H = w & 3, JH = lcol & 7;   // h[unit=w*8+(lcol&7)] position
    const int xr = tid >> 5, xk = tid & 31, xg = xk >> 3, xj = xk & 7;

    float c2[2] = {0.f, 0.f};

    // ---- encoder weights (fp16 hi/lo) + bias ----
    half8 whi[3][2], wlo[3][2];
    float bias[2];
    #pragma unroll
    for (int kt = 0; kt < 3; ++kt)
        #pragma unroll
        for (int tl = 0; tl < 2; ++tl) {
            const size_t base = (size_t)((((kt*8+w)*2+tl)*2+0)*64 + lane) * 16;
            whi[kt][tl] = *(const half8*)(ws + WS_ENC + base);
            wlo[kt][tl] = *(const half8*)(ws + WS_ENC + base + 64*16);
        }
    #pragma unroll
    for (int tl = 0; tl < 2; ++tl)
        bias[tl] = ((const float*)(ws + WS_BENC))[(w*2+tl)*64 + lane];

    // zero ENC h buf0 (blocks 0..7)
    for (int i = tid; i < 8*BLK/4; i += BDIM) ((uint32_t*)lds)[i] = 0u;
    // stage x[0] fp16, prefetch x[1]
    *(unsigned short*)(lds + ENC_X(0, xg) + xr*16 + xj*2) =
        f16_bits(x[((size_t)(row0 + xr)*T_SEQ + 0)*D_IN + xk]);
    float xreg = x[((size_t)(row0 + xr)*T_SEQ + 1)*D_IN + xk];
    lds_barrier();

    // gate selects + pointwise; returns 2 h values (rows rg*4+sel*2+{0,1})
    auto gates2h = [&](const float4_ &a0, const float4_ &a1, float &h0, float &h1) {
        float sw0[4], sw1[4];
        #pragma unroll
        for (int r = 0; r < 4; ++r) { sw0[r] = dpp_x8(a0[r]); sw1[r] = dpp_x8(a1[r]); }
        {
            const float ip = sel ? sw0[2] : a0[0];
            const float fp = sel ? a0[2]  : sw0[0];
            const float gp = sel ? sw1[2] : a1[0];
            const float op = sel ? a1[2]  : sw1[0];
            h0 = lstm_h(ip, fp, gp, op, c2[0]);
        }
        {
            const float ip = sel ? sw0[3] : a0[1];
            const float fp = sel ? a0[3]  : sw0[1];
            const float gp = sel ? sw1[3] : a1[1];
            const float op = sel ? a1[3]  : sw1[1];
            h1 = lstm_h(ip, fp, gp, op, c2[1]);
        }
    };

    // ---------------- encoder: 2-term fp16, 500 steps ----------------
    auto enc_gemm = [&](int CUR, float4_ (&acc)[2]) {
        const half8 ax  = *(const half8*)(lds + ENC_X(CUR, rg) + lcol*16);
        const half8 ah0 = *(const half8*)(lds + ENC_H(CUR, 0, rg) + lcol*16);
        const half8 ah1 = *(const half8*)(lds + ENC_H(CUR, 1, rg) + lcol*16);
        #pragma unroll
        for (int tl = 0; tl < 2; ++tl) {
            float4_ m = {bias[tl], bias[tl], bias[tl], bias[tl]};
            m = MFMAH(ax,  whi[0][tl], m);
            m = MFMAH(ah0, whi[1][tl], m);
            m = MFMAH(ah1, whi[2][tl], m);
            float4_ rs = MFMAH(ax,  wlo[0][tl], F4Z);
            rs = MFMAH(ah0, wlo[1][tl], rs);
            rs = MFMAH(ah1, wlo[2][tl], rs);
            acc[tl] = m + rs;
        }
    };

    auto enc_step = [&](int CUR, int t) {
        const int NXT = CUR ^ 1;
        float4_ acc[2];
        enc_gemm(CUR, acc);
        // x pipeline: stage x[t+1] (held in xreg-prev), load x[t+2]
        const float xold = xreg;
        const int tn = (t + 2 < T_SEQ) ? (t + 2) : (T_SEQ - 1);
        xreg = x[((size_t)(row0 + xr)*T_SEQ + tn)*D_IN + xk];
        if (t + 1 < T_SEQ)
            *(unsigned short*)(lds + ENC_X(NXT, xg) + xr*16 + xj*2) = f16_bits(xold);
        float h0, h1;
        gates2h(acc[0], acc[1], h0, h1);
        const int rb0 = (rg*4 + sel*2)*16 + JH*2;
        *(unsigned short*)(lds + ENC_H(NXT, KT_H, G_H) + rb0)      = f16_bits(h0);
        *(unsigned short*)(lds + ENC_H(NXT, KT_H, G_H) + rb0 + 16) = f16_bits(h1);
        lds_barrier();
    };

    int t = 0;
    for (int it = 0; it < 249; ++it) { enc_step(0, t); ++t; enc_step(1, t); ++t; }
    enc_step(0, t); ++t;          // t=498, writes ENC buf1
    {   // final encoder step t=499: read ENC buf1, write bf16 hi/lo into DEC buf0
        float4_ acc[2];
        enc_gemm(1, acc);
        float h0, h1;
        gates2h(acc[0], acc[1], h0, h1);
        unsigned short hh, ll;
        const int rb0 = (rg*4 + sel*2)*16 + JH*2;
        split_bf16(h0, hh, ll);
        *(unsigned short*)(lds + DEC_H(0, 0, KT_H, G_H) + rb0) = hh;
        *(unsigned short*)(lds + DEC_H(0, 1, KT_H, G_H) + rb0) = ll;
        split_bf16(h1, hh, ll);
        *(unsigned short*)(lds + DEC_H(0, 0, KT_H, G_H) + rb0 + 16) = hh;
        *(unsigned short*)(lds + DEC_H(0, 1, KT_H, G_H) + rb0 + 16) = ll;
        lds_barrier();
    }

    // ---------------- decoder (bf16 3-term) ----------------
    short8 qhi[2][2], qlo[2][2];
    auto load_dec = [&](size_t wsoff, size_t boff) {
        #pragma unroll
        for (int kt = 0; kt < 2; ++kt)
            #pragma unroll
            for (int tl = 0; tl < 2; ++tl) {
                const size_t base = (size_t)((((kt*8+w)*2+tl)*2+0)*64 + lane) * 16;
                qhi[kt][tl] = *(const short8*)(ws + wsoff + base);
                qlo[kt][tl] = *(const short8*)(ws + wsoff + base + 64*16);
            }
        #pragma unroll
        for (int tl = 0; tl < 2; ++tl)
            bias[tl] = ((const float*)(ws + boff))[(w*2+tl)*64 + lane];
    };
    auto ldh = [&](int buf, int hl, int kt) {
        return *(const short8*)(lds + DEC_H(buf, hl, kt, rg) + lcol*16);
    };
    auto pw_dec = [&](const float4_ &a0, const float4_ &a1, int nxt) {
        float h0, h1;
        gates2h(a0, a1, h0, h1);
        unsigned short hh, ll;
        const int rb0 = (rg*4 + sel*2)*16 + JH*2;
        split_bf16(h0, hh, ll);
        *(unsigned short*)(lds + DEC_H(nxt, 0, KT_H, G_H) + rb0) = hh;
        *(unsigned short*)(lds + DEC_H(nxt, 1, KT_H, G_H) + rb0) = ll;
        split_bf16(h1, hh, ll);
        *(unsigned short*)(lds + DEC_H(nxt, 0, KT_H, G_H) + rb0 + 16) = hh;
        *(unsigned short*)(lds + DEC_H(nxt, 1, KT_H, G_H) + rb0 + 16) = ll;
    };
    auto dec_gemm = [&](int CUR, float4_ (&acc)[2], short8 &a0, short8 &a1) {
        a0 = ldh(CUR, 0, 0); a1 = ldh(CUR, 0, 1);
        const short8 q0 = ldh(CUR, 1, 0), q1 = ldh(CUR, 1, 1);
        #pragma unroll
        for (int tl = 0; tl < 2; ++tl) {
            float4_ m = {bias[tl], bias[tl], bias[tl], bias[tl]};
            m = MFMAB(a0, qhi[0][tl], m);
            m = MFMAB(a1, qhi[1][tl], m);
            float4_ rw = MFMAB(a0, qlo[0][tl], F4Z);
            rw = MFMAB(a1, qlo[1][tl], rw);
            float4_ ra = MFMAB(q0, qhi[0][tl], F4Z);
            ra = MFMAB(q1, qhi[1][tl], ra);
            acc[tl] = (m + rw) + ra;
        }
    };

    // decoder step 0 (input zeros; Whh_d)
    load_dec(WS_DEC0, WS_BDEC0);
    {
        float4_ acc[2]; short8 a0, a1;
        dec_gemm(0, acc, a0, a1);
        pw_dec(acc[0], acc[1], 1);
        lds_barrier();
    }

    // decoder steps 1..499 (Wcomb; out hi-only as side-effect)
    load_dec(WS_COMB, WS_BCOMB);
    const bool ow  = (w == 0) || (w == 5);
    const int  tlo = (w == 0) ? 0 : 1;
    const int  ocol = tlo*16 + lcol;
    short8 woh[2] = {};
    float  bo = 0.f;
    if (ow) {
        #pragma unroll
        for (int kt = 0; kt < 2; ++kt)
            woh[kt] = *(const short8*)(ws + WS_OUT + (size_t)(((kt*2+tlo)*2+0)*64 + lane) * 16);
        bo = ((const float*)(ws + WS_BOUT))[tlo*64 + lane];
    }

    auto dec_step = [&](int CUR, int s) {
        float4_ acc[2]; short8 a0, a1;
        dec_gemm(CUR, acc, a0, a1);
        if (ow) {   // out_{s-1} = h_s @ Wout^T + bout  (hi-only: one-shot ~1e-3, no accumulation)
            float4_ om = {bo, bo, bo, bo};
            om = MFMAB(a0, woh[0], om);
            om = MFMAB(a1, woh[1], om);
            #pragma unroll
            for (int r = 0; r < 4; ++r)
                out[((size_t)(row0 + rg*4 + r)*T_SEQ + (s-1))*D_IN + ocol] = om[r];
        }
        pw_dec(acc[0], acc[1], CUR ^ 1);
        lds_barrier();
    };

    int s = 1;
    for (int it = 0; it < 249; ++it) { dec_step(1, s); ++s; dec_step(0, s); ++s; }
    dec_step(1, s);   // s=499; writes h_500 into DEC buf0

    // tail: out_499 = h_500 @ Wout^T + bout
    if (ow) {
        const short8 a0 = ldh(0, 0, 0), a1 = ldh(0, 0, 1);
        float4_ om = {bo, bo, bo, bo};
        om = MFMAB(a0, woh[0], om);
        om = MFMAB(a1, woh[1], om);
        #pragma unroll
        for (int r = 0; r < 4; ++r)
            out[((size_t)(row0 + rg*4 + r)*T_SEQ + (T_SEQ-1))*D_IN + ocol] = om[r];
    }
}

extern "C" void kernel_launch(void* const* d_in, const int* in_sizes, int n_in,
                              void* d_out, int out_size, void* d_ws, size_t ws_size,
                              hipStream_t stream) {
    (void)n_in; (void)ws_size; (void)out_size;
    const float* x     = (const float*)d_in[0];
    const float* Wih_e = (const float*)d_in[1];
    const float* Whh_e = (const float*)d_in[2];
    const float* b_e   = (const float*)d_in[3];
    const float* Wih_d = (const float*)d_in[4];
    const float* Whh_d = (const float*)d_in[5];
    const float* b_d   = (const float*)d_in[6];
    const float* Wout  = (const float*)d_in[7];
    const float* bout  = (const float*)d_in[8];
    float* out = (float*)d_out;

    const int B = in_sizes[0] / (T_SEQ * D_IN);   // 4096

    hipLaunchKernelGGL(prep_kernel, dim3(8), dim3(512), 0, stream,
                       Wih_e, Whh_e, b_e, Wih_d, Whh_d, b_d, Wout, bout, (char*)d_ws);
    hipLaunchKernelGGL(seq2seq_main, dim3(B / 16), dim3(BDIM), 0, stream,
                       x, (const char*)d_ws, out);
}

// Round 8
// 559.042 us; speedup vs baseline: 1.3800x; 1.0311x over previous
//
#include <hip/hip_runtime.h>
#include <stdint.h>

#define T_SEQ 500
#define D_IN  32
#define BDIM  256
#define ROWS  8

using short8  = __attribute__((ext_vector_type(8))) short;     // 8 bf16
using half8   = __attribute__((ext_vector_type(8))) _Float16;  // 8 fp16
using float4_ = __attribute__((ext_vector_type(4))) float;     // MFMA C/D frag

#define MFMAB(a,b,c) __builtin_amdgcn_mfma_f32_16x16x32_bf16((a),(b),(c),0,0,0)
#define MFMAH(a,b,c) __builtin_amdgcn_mfma_f32_16x16x32_f16((a),(b),(c),0,0,0)
#define F4Z (float4_){0.f,0.f,0.f,0.f}

// ---------------- LDS: 272B frag blocks (16 rows x 16B + 16B pad) ----------------
#define BLK 272
#define ENC_H(buf,kt,g)    ((((buf)*2+(kt))*4+(g))*BLK)                       // blocks 0..15
#define ENC_X(slot,g)      (16*BLK + ((slot)*4+(g))*BLK)                      // blocks 16..23
#define DEC_H(buf,hl,kt,g) (24*BLK + (((((buf)*2+(hl))*2+(kt))*4+(g))*BLK))   // blocks 24..55
#define LDS_BYTES (56*BLK)   // 15232 B

// ---------------- workspace (bytes) — same region sizes as r7 ----------------
#define WS_ENC   0                                // [kt3][w4][nt4][hl2][lane64] x16B (fp16)
#define WS_DEC0  (WS_ENC  + 3*4*4*2*64*16)        // 98304  (bf16 hi/lo)
#define WS_COMB  (WS_DEC0 + 2*4*4*2*64*16)        // 163840 (bf16 hi/lo)
#define WS_OUT   (WS_COMB + 2*4*4*2*64*16)        // 229376 : [kt2][ot2][hl2][lane64]
#define WS_BENC  (WS_OUT  + 2*2*2*64*16)          // 237568 : [w4][nt4][lane64] f32
#define WS_BDEC0 (WS_BENC  + 4*4*64*4)            // 241664
#define WS_BCOMB (WS_BDEC0 + 4*4*64*4)            // 245760
#define WS_BOUT  (WS_BCOMB + 4*4*64*4)            // 249856 : [ot2][lane64] f32

// gate scale folded into weights: i,f,o -> -log2(e); g -> +2*log2(e)
#define S_SIG  (-1.4426950408889634f)
#define S_TANH ( 2.8853900817779268f)

__device__ __forceinline__ void split_bf16(float v, unsigned short &hi, unsigned short &lo) {
    unsigned int b = __float_as_uint(v);
    hi = (unsigned short)(b >> 16);
    float vh = __uint_as_float(b & 0xFFFF0000u);
    lo = (unsigned short)(__float_as_uint(v - vh) >> 16);
}
__device__ __forceinline__ void split_f16(float v, unsigned short &hi, unsigned short &lo) {
    _Float16 h = (_Float16)v;
    _Float16 l = (_Float16)(v - (float)h);
    union { _Float16 f; unsigned short u; } a, b;
    a.f = h; b.f = l; hi = a.u; lo = b.u;
}
__device__ __forceinline__ unsigned short f16_bits(float v) {
    union { _Float16 f; unsigned short u; } t; t.f = (_Float16)v; return t.u;
}
// LDS-only barrier (no vmcnt drain)
__device__ __forceinline__ void lds_barrier() {
    asm volatile("s_waitcnt lgkmcnt(0)\n\ts_barrier" ::: "memory");
}
// fused-rcp LSTM pointwise (ip,fp,op pre-scaled by -log2e; gp by +2log2e)
__device__ __forceinline__ float lstm_h(float ip, float fp, float gp, float op, float &cc) {
    const float ei = __builtin_amdgcn_exp2f(ip);
    const float ef = __builtin_amdgcn_exp2f(fp);
    const float eg = __builtin_amdgcn_exp2f(gp);
    const float eo = __builtin_amdgcn_exp2f(op);
    const float pig = (eg - 1.0f) * __builtin_amdgcn_rcpf((1.0f + ei) * (1.0f + eg));
    const float fa  = __builtin_amdgcn_rcpf(1.0f + ef);
    cc = __builtin_fmaf(fa, cc, pig);
    const float ec = __builtin_amdgcn_exp2f(cc * -2.8853900817779268f);
    return (1.0f - ec) * __builtin_amdgcn_rcpf((1.0f + eo) * (1.0f + ec));
}

// ==================== prep kernel ====================
// NEW col map: wave w (0..3), tile nt = GATE nt, col c -> unit = w*16 + c, weight row n = nt*64 + unit
// frag element j of lane (rg=lane>>4): k = kt*32 + rg*8 + j
__global__ void __launch_bounds__(512)
prep_kernel(const float* __restrict__ Wih_e, const float* __restrict__ Whh_e,
            const float* __restrict__ b_e,
            const float* __restrict__ Wih_d, const float* __restrict__ Whh_d,
            const float* __restrict__ b_d,
            const float* __restrict__ Wout, const float* __restrict__ bout,
            char* __restrict__ ws)
{
    const int tid  = blockIdx.x * blockDim.x + threadIdx.x;
    const int nthr = gridDim.x * blockDim.x;

    // encoder fragments (fp16 hi/lo): slots (kt3, w4, nt4, lane64)
    for (int s = tid; s < 3*4*4*64; s += nthr) {
        const int lane = s & 63, nt = (s >> 6) & 3, w = (s >> 8) & 3, kt = s >> 10;
        const int rg = lane >> 4;
        const int n = nt*64 + w*16 + (lane & 15);
        const float sc = (nt == 2) ? S_TANH : S_SIG;
        short8 hi8, lo8;
        #pragma unroll
        for (int j = 0; j < 8; ++j) {
            const int k = kt*32 + rg*8 + j;
            const float wv = sc * ((k < 32) ? Wih_e[n*D_IN + k] : Whh_e[n*64 + k - 32]);
            unsigned short h_, l_; split_f16(wv, h_, l_);
            hi8[j] = (short)h_; lo8[j] = (short)l_;
        }
        const size_t base = (size_t)(((((kt*4+w)*4+nt)*2+0)*64 + lane)) * 16;
        *(short8*)(ws + WS_ENC + base)           = hi8;
        *(short8*)(ws + WS_ENC + base + 64*16)   = lo8;
    }

    // decoder step-0 (Whh_d) and combined (Whh_d + Wih_d@Wout), bf16 hi/lo: (kt2, w4, nt4, lane64)
    for (int s = tid; s < 2*4*4*64; s += nthr) {
        const int lane = s & 63, nt = (s >> 6) & 3, w = (s >> 8) & 3, kt = s >> 10;
        const int rg = lane >> 4;
        const int n = nt*64 + w*16 + (lane & 15);
        const float sc = (nt == 2) ? S_TANH : S_SIG;
        short8 h0v, l0v, hcv, lcv;
        #pragma unroll
        for (int j = 0; j < 8; ++j) {
            const int k = kt*32 + rg*8 + j;
            const float w0 = Whh_d[n*64 + k];
            float a = w0;
            for (int d = 0; d < 32; ++d) a += Wih_d[n*D_IN + d] * Wout[d*64 + k];
            unsigned short h_, l_;
            split_bf16(sc * w0, h_, l_); h0v[j] = (short)h_; l0v[j] = (short)l_;
            split_bf16(sc * a,  h_, l_); hcv[j] = (short)h_; lcv[j] = (short)l_;
        }
        const size_t base = (size_t)(((((kt*4+w)*4+nt)*2+0)*64 + lane)) * 16;
        *(short8*)(ws + WS_DEC0 + base)         = h0v;
        *(short8*)(ws + WS_DEC0 + base + 64*16) = l0v;
        *(short8*)(ws + WS_COMB + base)         = hcv;
        *(short8*)(ws + WS_COMB + base + 64*16) = lcv;
    }

    // Wout fragments (bf16): (kt2, ot2, lane64); col = ot*16 + (lane&15)
    for (int s = tid; s < 2*2*64; s += nthr) {
        const int lane = s & 63, ot = (s >> 6) & 1, kt = s >> 7;
        const int rg = lane >> 4;
        const int ocol = ot*16 + (lane & 15);
        short8 hi8, lo8;
        #pragma unroll
        for (int j = 0; j < 8; ++j) {
            const int k = kt*32 + rg*8 + j;
            unsigned short h_, l_; split_bf16(Wout[ocol*64 + k], h_, l_);
            hi8[j] = (short)h_; lo8[j] = (short)l_;
        }
        const size_t base = (size_t)((((kt*2+ot)*2+0)*64 + lane)) * 16;
        *(short8*)(ws + WS_OUT + base)         = hi8;
        *(short8*)(ws + WS_OUT + base + 64*16) = lo8;
    }

    // gate biases: (w4, nt4, lane64)
    for (int s = tid; s < 4*4*64; s += nthr) {
        const int lane = s & 63, nt = (s >> 6) & 3, w = s >> 8;
        const int n = nt*64 + w*16 + (lane & 15);
        const float sc = (nt == 2) ? S_TANH : S_SIG;
        float a = b_d[n];
        for (int d = 0; d < 32; ++d) a += Wih_d[n*D_IN + d] * bout[d];
        ((float*)(ws + WS_BENC))[s]  = sc * b_e[n];
        ((float*)(ws + WS_BDEC0))[s] = sc * b_d[n];
        ((float*)(ws + WS_BCOMB))[s] = sc * a;
    }
    for (int s = tid; s < 2*64; s += nthr)
        ((float*)(ws + WS_BOUT))[s] = bout[(s >> 6)*16 + (s & 15)];
}

// ==================== main kernel: 512 blocks x 4 waves x 8 rows ====================
extern "C" __global__ void __launch_bounds__(BDIM, 2)
seq2seq_main(const float* __restrict__ x, const char* __restrict__ ws,
             float* __restrict__ out)
{
    __shared__ __align__(16) char lds[LDS_BYTES];

    const int tid  = threadIdx.x;
    const int w    = tid >> 6;            // 0..3
    const int lane = tid & 63;
    const int rg   = lane >> 4;
    const int lcol = lane & 15;
    const int row0 = blockIdx.x * ROWS;

    // h position of this lane's unit = w*16 + lcol
    const int KT_H = w >> 1;
    const int G_H  = ((w & 1) << 1) | (lcol >> 3);
    const int JH   = lcol & 7;
    // x staging: thread stages 1 value: batch row srow, k sk; tile row xtr (real rows at r&3<2)
    const int srow = tid >> 5, sk = tid & 31;
    const int xg = sk >> 3, xj = sk & 7;
    const int xtr = ((srow >> 1) << 2) | (srow & 1);

    float c2[2] = {0.f, 0.f};

    // ---- encoder weights (fp16 hi/lo), 4 gate-tiles ----
    half8 whi[3][4], wlo[3][4];
    float bias[4];
    #pragma unroll
    for (int kt = 0; kt < 3; ++kt)
        #pragma unroll
        for (int nt = 0; nt < 4; ++nt) {
            const size_t base = (size_t)(((((kt*4+w)*4+nt)*2+0)*64 + lane)) * 16;
            whi[kt][nt] = *(const half8*)(ws + WS_ENC + base);
            wlo[kt][nt] = *(const half8*)(ws + WS_ENC + base + 64*16);
        }
    #pragma unroll
    for (int nt = 0; nt < 4; ++nt)
        bias[nt] = ((const float*)(ws + WS_BENC))[(w*4+nt)*64 + lane];

    // zero ALL LDS (padding rows must stay 0 forever)
    for (int i = tid; i < LDS_BYTES/4; i += BDIM) ((uint32_t*)lds)[i] = 0u;

    // stage x[0]; prefetch x[1], x[2]
    *(unsigned short*)(lds + ENC_X(0, xg) + xtr*16 + xj*2) =
        f16_bits(x[((size_t)(row0 + srow)*T_SEQ + 0)*D_IN + sk]);
    float xc = x[((size_t)(row0 + srow)*T_SEQ + 1)*D_IN + sk];
    float xn = x[((size_t)(row0 + srow)*T_SEQ + 2)*D_IN + sk];
    lds_barrier();

    // ---------------- encoder: fp16 2-term, no-exchange ----------------
    // returns gate values for the lane's 2 real rows (C/D regs 0,1)
    auto enc_gemm = [&](int CUR, float (&v0)[4], float (&v1)[4]) {
        const half8 ax  = *(const half8*)(lds + ENC_X(CUR, rg) + lcol*16);
        const half8 ah0 = *(const half8*)(lds + ENC_H(CUR, 0, rg) + lcol*16);
        const half8 ah1 = *(const half8*)(lds + ENC_H(CUR, 1, rg) + lcol*16);
        #pragma unroll
        for (int nt = 0; nt < 4; ++nt) {
            float4_ m = MFMAH(ax,  whi[0][nt], F4Z);
            m = MFMAH(ah0, whi[1][nt], m);
            m = MFMAH(ah1, whi[2][nt], m);
            float4_ rs = MFMAH(ax,  wlo[0][nt], F4Z);
            rs = MFMAH(ah0, wlo[1][nt], rs);
            rs = MFMAH(ah1, wlo[2][nt], rs);
            v0[nt] = m[0] + rs[0] + bias[nt];
            v1[nt] = m[1] + rs[1] + bias[nt];
        }
    };

    auto enc_step = [&](int CUR, int t) {
        const int NXT = CUR ^ 1;
        float v0[4], v1[4];
        enc_gemm(CUR, v0, v1);
        // x pipeline: stage x[t+1], load x[t+3]
        const float xold = xc; xc = xn;
        const int tn = (t + 3 < T_SEQ) ? (t + 3) : (T_SEQ - 1);
        xn = x[((size_t)(row0 + srow)*T_SEQ + tn)*D_IN + sk];
        if (t + 1 < T_SEQ)
            *(unsigned short*)(lds + ENC_X(NXT, xg) + xtr*16 + xj*2) = f16_bits(xold);
        const float h0 = lstm_h(v0[0], v0[1], v0[2], v0[3], c2[0]);
        const float h1 = lstm_h(v1[0], v1[1], v1[2], v1[3], c2[1]);
        const int rb = rg*64 + JH*2;   // tile rows rg*4, rg*4+1
        *(unsigned short*)(lds + ENC_H(NXT, KT_H, G_H) + rb)      = f16_bits(h0);
        *(unsigned short*)(lds + ENC_H(NXT, KT_H, G_H) + rb + 16) = f16_bits(h1);
        lds_barrier();
    };

    int t = 0;
    for (int it = 0; it < 249; ++it) { enc_step(0, t); ++t; enc_step(1, t); ++t; }
    enc_step(0, 498);
    {   // final encoder step t=499: read buf1, write bf16 hi/lo h_enc into DEC buf0
        float v0[4], v1[4];
        enc_gemm(1, v0, v1);
        const float h0 = lstm_h(v0[0], v0[1], v0[2], v0[3], c2[0]);
        const float h1 = lstm_h(v1[0], v1[1], v1[2], v1[3], c2[1]);
        unsigned short hh, ll;
        const int rb = rg*64 + JH*2;
        split_bf16(h0, hh, ll);
        *(unsigned short*)(lds + DEC_H(0, 0, KT_H, G_H) + rb) = hh;
        *(unsigned short*)(lds + DEC_H(0, 1, KT_H, G_H) + rb) = ll;
        split_bf16(h1, hh, ll);
        *(unsigned short*)(lds + DEC_H(0, 0, KT_H, G_H) + rb + 16) = hh;
        *(unsigned short*)(lds + DEC_H(0, 1, KT_H, G_H) + rb + 16) = ll;
        lds_barrier();
    }

    // ---------------- decoder: bf16 3-term, no-exchange ----------------
    short8 qhi[2][4], qlo[2][4];
    auto load_dec = [&](size_t wsoff, size_t boff) {
        #pragma unroll
        for (int kt = 0; kt < 2; ++kt)
            #pragma unroll
            for (int nt = 0; nt < 4; ++nt) {
                const size_t base = (size_t)(((((kt*4+w)*4+nt)*2+0)*64 + lane)) * 16;
                qhi[kt][nt] = *(const short8*)(ws + wsoff + base);
                qlo[kt][nt] = *(const short8*)(ws + wsoff + base + 64*16);
            }
        #pragma unroll
        for (int nt = 0; nt < 4; ++nt)
            bias[nt] = ((const float*)(ws + boff))[(w*4+nt)*64 + lane];
    };
    auto pw_dec = [&](const float (&v0)[4], const float (&v1)[4], int nxt) {
        const float h0 = lstm_h(v0[0], v0[1], v0[2], v0[3], c2[0]);
        const float h1 = lstm_h(v1[0], v1[1], v1[2], v1[3], c2[1]);
        unsigned short hh, ll;
        const int rb = rg*64 + JH*2;
        split_bf16(h0, hh, ll);
        *(unsigned short*)(lds + DEC_H(nxt, 0, KT_H, G_H) + rb) = hh;
        *(unsigned short*)(lds + DEC_H(nxt, 1, KT_H, G_H) + rb) = ll;
        split_bf16(h1, hh, ll);
        *(unsigned short*)(lds + DEC_H(nxt, 0, KT_H, G_H) + rb + 16) = hh;
        *(unsigned short*)(lds + DEC_H(nxt, 1, KT_H, G_H) + rb + 16) = ll;
    };

    // out-wave setup: wave 0 -> out cols 0..15, wave 2 -> cols 16..31 (different SIMDs)
    const bool ow  = (w == 0) || (w == 2);
    const int  tlo = w >> 1;
    const int  ocol = tlo*16 + lcol;
    short8 woh[2] = {};
    float  bo = 0.f;
    if (ow) {
        #pragma unroll
        for (int kt = 0; kt < 2; ++kt)
            woh[kt] = *(const short8*)(ws + WS_OUT + (size_t)((((kt*2+tlo)*2+0)*64 + lane)) * 16);
        bo = ((const float*)(ws + WS_BOUT))[tlo*64 + lane];
    }

    // decoder step 0 (input zeros; Whh_d)
    load_dec(WS_DEC0, WS_BDEC0);
    {
        const short8 a0 = *(const short8*)(lds + DEC_H(0,0,0,rg) + lcol*16);
        const short8 a1 = *(const short8*)(lds + DEC_H(0,0,1,rg) + lcol*16);
        const short8 q0 = *(const short8*)(lds + DEC_H(0,1,0,rg) + lcol*16);
        const short8 q1 = *(const short8*)(lds + DEC_H(0,1,1,rg) + lcol*16);
        float v0[4], v1[4];
        #pragma unroll
        for (int nt = 0; nt < 4; ++nt) {
            float4_ m = MFMAB(a0, qhi[0][nt], F4Z);
            m = MFMAB(a1, qhi[1][nt], m);
            float4_ rw = MFMAB(a0, qlo[0][nt], F4Z);
            rw = MFMAB(a1, qlo[1][nt], rw);
            float4_ ra = MFMAB(q0, qhi[0][nt], F4Z);
            ra = MFMAB(q1, qhi[1][nt], ra);
            v0[nt] = (m[0] + rw[0]) + (ra[0] + bias[nt]);
            v1[nt] = (m[1] + rw[1]) + (ra[1] + bias[nt]);
        }
        pw_dec(v0, v1, 1);
        lds_barrier();
    }

    // decoder steps 1..499 (Wcomb; out hi-only side-store)
    load_dec(WS_COMB, WS_BCOMB);

    auto dec_step = [&](int CUR, int s) {
        const short8 a0 = *(const short8*)(lds + DEC_H(CUR,0,0,rg) + lcol*16);
        const short8 a1 = *(const short8*)(lds + DEC_H(CUR,0,1,rg) + lcol*16);
        const short8 q0 = *(const short8*)(lds + DEC_H(CUR,1,0,rg) + lcol*16);
        const short8 q1 = *(const short8*)(lds + DEC_H(CUR,1,1,rg) + lcol*16);
        float v0[4], v1[4];
        #pragma unroll
        for (int nt = 0; nt < 4; ++nt) {
            float4_ m = MFMAB(a0, qhi[0][nt], F4Z);
            m = MFMAB(a1, qhi[1][nt], m);
            float4_ rw = MFMAB(a0, qlo[0][nt], F4Z);
            rw = MFMAB(a1, qlo[1][nt], rw);
            float4_ ra = MFMAB(q0, qhi[0][nt], F4Z);
            ra = MFMAB(q1, qhi[1][nt], ra);
            v0[nt] = (m[0] + rw[0]) + (ra[0] + bias[nt]);
            v1[nt] = (m[1] + rw[1]) + (ra[1] + bias[nt]);
        }
        if (ow) {   // out_{s-1} = h_s @ Wout^T + bout (hi-only); stores fly across barrier
            float4_ om = {bo, bo, bo, bo};
            om = MFMAB(a0, woh[0], om);
            om = MFMAB(a1, woh[1], om);
            out[((size_t)(row0 + 2*rg + 0)*T_SEQ + (s-1))*D_IN + ocol] = om[0];
            out[((size_t)(row0 + 2*rg + 1)*T_SEQ + (s-1))*D_IN + ocol] = om[1];
        }
        pw_dec(v0, v1, CUR ^ 1);
        lds_barrier();
    };

    int s = 1;
    for (int it = 0; it < 249; ++it) { dec_step(1, s); ++s; dec_step(0, s); ++s; }
    dec_step(1, 499);   // writes h_500 into DEC buf0

    // tail: out_499 = h_500 @ Wout^T + bout
    if (ow) {
        const short8 a0 = *(const short8*)(lds + DEC_H(0,0,0,rg) + lcol*16);
        const short8 a1 = *(const short8*)(lds + DEC_H(0,0,1,rg) + lcol*16);
        float4_ om = {bo, bo, bo, bo};
        om = MFMAB(a0, woh[0], om);
        om = MFMAB(a1, woh[1], om);
        out[((size_t)(row0 + 2*rg + 0)*T_SEQ + (T_SEQ-1))*D_IN + ocol] = om[0];
        out[((size_t)(row0 + 2*rg + 1)*T_SEQ + (T_SEQ-1))*D_IN + ocol] = om[1];
    }
}

extern "C" void kernel_launch(void* const* d_in, const int* in_sizes, int n_in,
                              void* d_out, int out_size, void* d_ws, size_t ws_size,
                              hipStream_t stream) {
    (void)n_in; (void)ws_size; (void)out_size;
    const float* x     = (const float*)d_in[0];
    const float* Wih_e = (const float*)d_in[1];
    const float* Whh_e = (const float*)d_in[2];
    const float* b_e   = (const float*)d_in[3];
    const float* Wih_d = (const float*)d_in[4];
    const float* Whh_d = (const float*)d_in[5];
    const float* b_d   = (const float*)d_in[6];
    const float* Wout  = (const float*)d_in[7];
    const float* bout  = (const float*)d_in[8];
    float* out = (float*)d_out;

    const int B = in_sizes[0] / (T_SEQ * D_IN);   // 4096

    hipLaunchKernelGGL(prep_kernel, dim3(8), dim3(512), 0, stream,
                       Wih_e, Whh_e, b_e, Wih_d, Whh_d, b_d, Wout, bout, (char*)d_ws);
    hipLaunchKernelGGL(seq2seq_main, dim3(B / ROWS), dim3(BDIM), 0, stream,
                       x, (const char*)d_ws, out);
}

// Round 9
// 491.469 us; speedup vs baseline: 1.5697x; 1.1375x over previous
//
#include <hip/hip_runtime.h>
#include <stdint.h>

#define T_SEQ 500
#define D_IN  32
#define BDIM  256
#define ROWS  8

using short8  = __attribute__((ext_vector_type(8))) short;     // 8 bf16
using half8   = __attribute__((ext_vector_type(8))) _Float16;  // 8 fp16
using float4_ = __attribute__((ext_vector_type(4))) float;     // MFMA C/D frag

#define MFMAH(a,b,c) __builtin_amdgcn_mfma_f32_16x16x32_f16((a),(b),(c),0,0,0)
#define F4Z (float4_){0.f,0.f,0.f,0.f}

// ---------------- LDS: 272B frag blocks (16 rows x 16B + 16B pad) ----------------
#define BLK 272
#define ENC_H(buf,kt,g)  ((((buf)*2+(kt))*4+(g))*BLK)                   // blocks 0..15
#define ENC_X(slot,g)    (16*BLK + ((slot)*4+(g))*BLK)                  // blocks 16..23
#define DEC_H(buf,kt,g)  (24*BLK + ((((buf)*2+(kt))*4+(g))*BLK))        // blocks 24..39
#define LDS_BYTES (40*BLK)   // 10880 B

// ---------------- workspace (bytes) — same region sizes as r8, fp16 payloads ----------------
#define WS_ENC   0                                // [kt3][w4][nt4][hl2][lane64] x16B (fp16)
#define WS_DEC0  (WS_ENC  + 3*4*4*2*64*16)        // 98304  (fp16 hi/lo)
#define WS_COMB  (WS_DEC0 + 2*4*4*2*64*16)        // 163840 (fp16 hi/lo)
#define WS_OUT   (WS_COMB + 2*4*4*2*64*16)        // 229376 : [kt2][ot2][hl2][lane64] (fp16)
#define WS_BENC  (WS_OUT  + 2*2*2*64*16)          // 237568 : [w4][nt4][lane64] f32
#define WS_BDEC0 (WS_BENC  + 4*4*64*4)            // 241664
#define WS_BCOMB (WS_BDEC0 + 4*4*64*4)            // 245760
#define WS_BOUT  (WS_BCOMB + 4*4*64*4)            // 249856 : [ot2][lane64] f32

// gate scale folded into weights: i,f,o -> -log2(e); g -> +2*log2(e)
#define S_SIG  (-1.4426950408889634f)
#define S_TANH ( 2.8853900817779268f)

__device__ __forceinline__ void split_f16(float v, unsigned short &hi, unsigned short &lo) {
    _Float16 h = (_Float16)v;
    _Float16 l = (_Float16)(v - (float)h);
    union { _Float16 f; unsigned short u; } a, b;
    a.f = h; b.f = l; hi = a.u; lo = b.u;
}
__device__ __forceinline__ unsigned short f16_bits(float v) {
    union { _Float16 f; unsigned short u; } t; t.f = (_Float16)v; return t.u;
}
// LDS-only barrier (no vmcnt drain)
__device__ __forceinline__ void lds_barrier() {
    asm volatile("s_waitcnt lgkmcnt(0)\n\ts_barrier" ::: "memory");
}
// fused-rcp LSTM pointwise (ip,fp,op pre-scaled by -log2e; gp by +2log2e)
__device__ __forceinline__ float lstm_h(float ip, float fp, float gp, float op, float &cc) {
    const float ei = __builtin_amdgcn_exp2f(ip);
    const float ef = __builtin_amdgcn_exp2f(fp);
    const float eg = __builtin_amdgcn_exp2f(gp);
    const float eo = __builtin_amdgcn_exp2f(op);
    const float pig = (eg - 1.0f) * __builtin_amdgcn_rcpf((1.0f + ei) * (1.0f + eg));
    const float fa  = __builtin_amdgcn_rcpf(1.0f + ef);
    cc = __builtin_fmaf(fa, cc, pig);
    const float ec = __builtin_amdgcn_exp2f(cc * -2.8853900817779268f);
    return (1.0f - ec) * __builtin_amdgcn_rcpf((1.0f + eo) * (1.0f + ec));
}

// ==================== prep kernel ====================
// col map: wave w (0..3), tile nt = GATE, col c -> unit = w*16 + c, weight row n = nt*64 + unit
// frag element j of lane (rg=lane>>4): k = kt*32 + rg*8 + j
__global__ void __launch_bounds__(512)
prep_kernel(const float* __restrict__ Wih_e, const float* __restrict__ Whh_e,
            const float* __restrict__ b_e,
            const float* __restrict__ Wih_d, const float* __restrict__ Whh_d,
            const float* __restrict__ b_d,
            const float* __restrict__ Wout, const float* __restrict__ bout,
            char* __restrict__ ws)
{
    const int tid  = blockIdx.x * blockDim.x + threadIdx.x;
    const int nthr = gridDim.x * blockDim.x;

    // encoder fragments (fp16 hi/lo): slots (kt3, w4, nt4, lane64)
    for (int s = tid; s < 3*4*4*64; s += nthr) {
        const int lane = s & 63, nt = (s >> 6) & 3, w = (s >> 8) & 3, kt = s >> 10;
        const int rg = lane >> 4;
        const int n = nt*64 + w*16 + (lane & 15);
        const float sc = (nt == 2) ? S_TANH : S_SIG;
        short8 hi8, lo8;
        #pragma unroll
        for (int j = 0; j < 8; ++j) {
            const int k = kt*32 + rg*8 + j;
            const float wv = sc * ((k < 32) ? Wih_e[n*D_IN + k] : Whh_e[n*64 + k - 32]);
            unsigned short h_, l_; split_f16(wv, h_, l_);
            hi8[j] = (short)h_; lo8[j] = (short)l_;
        }
        const size_t base = (size_t)(((((kt*4+w)*4+nt)*2+0)*64 + lane)) * 16;
        *(short8*)(ws + WS_ENC + base)           = hi8;
        *(short8*)(ws + WS_ENC + base + 64*16)   = lo8;
    }

    // decoder step-0 (Whh_d) and combined (Whh_d + Wih_d@Wout), fp16 hi/lo: (kt2, w4, nt4, lane64)
    for (int s = tid; s < 2*4*4*64; s += nthr) {
        const int lane = s & 63, nt = (s >> 6) & 3, w = (s >> 8) & 3, kt = s >> 10;
        const int rg = lane >> 4;
        const int n = nt*64 + w*16 + (lane & 15);
        const float sc = (nt == 2) ? S_TANH : S_SIG;
        short8 h0v, l0v, hcv, lcv;
        #pragma unroll
        for (int j = 0; j < 8; ++j) {
            const int k = kt*32 + rg*8 + j;
            const float w0 = Whh_d[n*64 + k];
            float a = w0;
            for (int d = 0; d < 32; ++d) a += Wih_d[n*D_IN + d] * Wout[d*64 + k];
            unsigned short h_, l_;
            split_f16(sc * w0, h_, l_); h0v[j] = (short)h_; l0v[j] = (short)l_;
            split_f16(sc * a,  h_, l_); hcv[j] = (short)h_; lcv[j] = (short)l_;
        }
        const size_t base = (size_t)(((((kt*4+w)*4+nt)*2+0)*64 + lane)) * 16;
        *(short8*)(ws + WS_DEC0 + base)         = h0v;
        *(short8*)(ws + WS_DEC0 + base + 64*16) = l0v;
        *(short8*)(ws + WS_COMB + base)         = hcv;
        *(short8*)(ws + WS_COMB + base + 64*16) = lcv;
    }

    // Wout fragments (fp16, hi used): (kt2, ot2, lane64); col = ot*16 + (lane&15)
    for (int s = tid; s < 2*2*64; s += nthr) {
        const int lane = s & 63, ot = (s >> 6) & 1, kt = s >> 7;
        const int rg = lane >> 4;
        const int ocol = ot*16 + (lane & 15);
        short8 hi8, lo8;
        #pragma unroll
        for (int j = 0; j < 8; ++j) {
            const int k = kt*32 + rg*8 + j;
            unsigned short h_, l_; split_f16(Wout[ocol*64 + k], h_, l_);
            hi8[j] = (short)h_; lo8[j] = (short)l_;
        }
        const size_t base = (size_t)((((kt*2+ot)*2+0)*64 + lane)) * 16;
        *(short8*)(ws + WS_OUT + base)         = hi8;
        *(short8*)(ws + WS_OUT + base + 64*16) = lo8;
    }

    // gate biases: (w4, nt4, lane64)
    for (int s = tid; s < 4*4*64; s += nthr) {
        const int lane = s & 63, nt = (s >> 6) & 3, w = s >> 8;
        const int n = nt*64 + w*16 + (lane & 15);
        const float sc = (nt == 2) ? S_TANH : S_SIG;
        float a = b_d[n];
        for (int d = 0; d < 32; ++d) a += Wih_d[n*D_IN + d] * bout[d];
        ((float*)(ws + WS_BENC))[s]  = sc * b_e[n];
        ((float*)(ws + WS_BDEC0))[s] = sc * b_d[n];
        ((float*)(ws + WS_BCOMB))[s] = sc * a;
    }
    for (int s = tid; s < 2*64; s += nthr)
        ((float*)(ws + WS_BOUT))[s] = bout[(s >> 6)*16 + (s & 15)];
}

// ==================== main kernel: 512 blocks x 4 waves x 8 rows ====================
extern "C" __global__ void __launch_bounds__(BDIM, 2)
seq2seq_main(const float* __restrict__ x, const char* __restrict__ ws,
             float* __restrict__ out)
{
    __shared__ __align__(16) char lds[LDS_BYTES];

    const int tid  = threadIdx.x;
    const int w    = tid >> 6;            // 0..3
    const int lane = tid & 63;
    const int rg   = lane >> 4;
    const int lcol = lane & 15;
    const int row0 = blockIdx.x * ROWS;

    // h position of this lane's unit = w*16 + lcol  (k = unit)
    const int KT_H = w >> 1;
    const int G_H  = ((w & 1) << 1) | (lcol >> 3);
    const int JH   = lcol & 7;
    // x staging: batch row srow, k sk; tile row xtr (real rows at tile rows rg*4+{0,1})
    const int srow = tid >> 5, sk = tid & 31;
    const int xg = sk >> 3, xj = sk & 7;
    const int xtr = ((srow >> 1) << 2) | (srow & 1);

    float c2[2] = {0.f, 0.f};

    // ---- encoder weights (fp16 hi/lo) + bias ----
    half8 whi[3][4], wlo[3][4];
    float bias[4];
    #pragma unroll
    for (int kt = 0; kt < 3; ++kt)
        #pragma unroll
        for (int nt = 0; nt < 4; ++nt) {
            const size_t base = (size_t)(((((kt*4+w)*4+nt)*2+0)*64 + lane)) * 16;
            whi[kt][nt] = *(const half8*)(ws + WS_ENC + base);
            wlo[kt][nt] = *(const half8*)(ws + WS_ENC + base + 64*16);
        }
    #pragma unroll
    for (int nt = 0; nt < 4; ++nt)
        bias[nt] = ((const float*)(ws + WS_BENC))[(w*4+nt)*64 + lane];

    // zero ALL LDS (padding rows must stay 0 forever)
    for (int i = tid; i < LDS_BYTES/4; i += BDIM) ((uint32_t*)lds)[i] = 0u;

    // stage x[0]; prefetch x[1], x[2]
    *(unsigned short*)(lds + ENC_X(0, xg) + xtr*16 + xj*2) =
        f16_bits(x[((size_t)(row0 + srow)*T_SEQ + 0)*D_IN + sk]);
    float xc = x[((size_t)(row0 + srow)*T_SEQ + 1)*D_IN + sk];
    float xn = x[((size_t)(row0 + srow)*T_SEQ + 2)*D_IN + sk];
    lds_barrier();

    // ---------------- encoder: fp16 2-term, no-exchange ----------------
    auto enc_gemm = [&](int CUR, float (&v0)[4], float (&v1)[4]) {
        const half8 ax  = *(const half8*)(lds + ENC_X(CUR, rg) + lcol*16);
        const half8 ah0 = *(const half8*)(lds + ENC_H(CUR, 0, rg) + lcol*16);
        const half8 ah1 = *(const half8*)(lds + ENC_H(CUR, 1, rg) + lcol*16);
        #pragma unroll
        for (int nt = 0; nt < 4; ++nt) {
            float4_ m = {bias[nt], bias[nt], bias[nt], bias[nt]};
            m = MFMAH(ax,  whi[0][nt], m);
            m = MFMAH(ah0, whi[1][nt], m);
            m = MFMAH(ah1, whi[2][nt], m);
            float4_ rs = MFMAH(ax,  wlo[0][nt], F4Z);
            rs = MFMAH(ah0, wlo[1][nt], rs);
            rs = MFMAH(ah1, wlo[2][nt], rs);
            v0[nt] = m[0] + rs[0];
            v1[nt] = m[1] + rs[1];
        }
    };

    auto enc_step = [&](int CUR, int t) {
        const int NXT = CUR ^ 1;
        float v0[4], v1[4];
        enc_gemm(CUR, v0, v1);
        const float xold = xc; xc = xn;
        const int tn = (t + 3 < T_SEQ) ? (t + 3) : (T_SEQ - 1);
        xn = x[((size_t)(row0 + srow)*T_SEQ + tn)*D_IN + sk];
        if (t + 1 < T_SEQ)
            *(unsigned short*)(lds + ENC_X(NXT, xg) + xtr*16 + xj*2) = f16_bits(xold);
        const float h0 = lstm_h(v0[0], v0[1], v0[2], v0[3], c2[0]);
        const float h1 = lstm_h(v1[0], v1[1], v1[2], v1[3], c2[1]);
        const int rb = rg*64 + JH*2;   // tile rows rg*4, rg*4+1
        *(unsigned short*)(lds + ENC_H(NXT, KT_H, G_H) + rb)      = f16_bits(h0);
        *(unsigned short*)(lds + ENC_H(NXT, KT_H, G_H) + rb + 16) = f16_bits(h1);
        lds_barrier();
    };

    int t = 0;
    for (int it = 0; it < 249; ++it) { enc_step(0, t); ++t; enc_step(1, t); ++t; }
    enc_step(0, 498);
    {   // final encoder step t=499: read buf1, write fp16 h_enc into DEC buf0
        float v0[4], v1[4];
        enc_gemm(1, v0, v1);
        const float h0 = lstm_h(v0[0], v0[1], v0[2], v0[3], c2[0]);
        const float h1 = lstm_h(v1[0], v1[1], v1[2], v1[3], c2[1]);
        const int rb = rg*64 + JH*2;
        *(unsigned short*)(lds + DEC_H(0, KT_H, G_H) + rb)      = f16_bits(h0);
        *(unsigned short*)(lds + DEC_H(0, KT_H, G_H) + rb + 16) = f16_bits(h1);
        lds_barrier();
    }

    // ---------------- decoder: fp16 2-term, no-exchange ----------------
    half8 qhi[2][4], qlo[2][4];
    auto load_dec = [&](size_t wsoff, size_t boff) {
        #pragma unroll
        for (int kt = 0; kt < 2; ++kt)
            #pragma unroll
            for (int nt = 0; nt < 4; ++nt) {
                const size_t base = (size_t)(((((kt*4+w)*4+nt)*2+0)*64 + lane)) * 16;
                qhi[kt][nt] = *(const half8*)(ws + wsoff + base);
                qlo[kt][nt] = *(const half8*)(ws + wsoff + base + 64*16);
            }
        #pragma unroll
        for (int nt = 0; nt < 4; ++nt)
            bias[nt] = ((const float*)(ws + boff))[(w*4+nt)*64 + lane];
    };
    auto pw_dec = [&](const float (&v0)[4], const float (&v1)[4], int nxt) {
        const float h0 = lstm_h(v0[0], v0[1], v0[2], v0[3], c2[0]);
        const float h1 = lstm_h(v1[0], v1[1], v1[2], v1[3], c2[1]);
        const int rb = rg*64 + JH*2;
        *(unsigned short*)(lds + DEC_H(nxt, KT_H, G_H) + rb)      = f16_bits(h0);
        *(unsigned short*)(lds + DEC_H(nxt, KT_H, G_H) + rb + 16) = f16_bits(h1);
    };

    // out-wave setup: wave 0 -> cols 0..15, wave 2 -> cols 16..31 (different SIMDs)
    const bool ow  = (w == 0) || (w == 2);
    const int  tlo = w >> 1;
    const int  ocol = tlo*16 + lcol;
    half8 woh[2] = {};
    float bo = 0.f;
    if (ow) {
        #pragma unroll
        for (int kt = 0; kt < 2; ++kt)
            woh[kt] = *(const half8*)(ws + WS_OUT + (size_t)((((kt*2+tlo)*2+0)*64 + lane)) * 16);
        bo = ((const float*)(ws + WS_BOUT))[tlo*64 + lane];
    }

    // decoder step 0 (input zeros; Whh_d)
    load_dec(WS_DEC0, WS_BDEC0);
    {
        const half8 a0 = *(const half8*)(lds + DEC_H(0,0,rg) + lcol*16);
        const half8 a1 = *(const half8*)(lds + DEC_H(0,1,rg) + lcol*16);
        float v0[4], v1[4];
        #pragma unroll
        for (int nt = 0; nt < 4; ++nt) {
            float4_ m = {bias[nt], bias[nt], bias[nt], bias[nt]};
            m = MFMAH(a0, qhi[0][nt], m);
            m = MFMAH(a1, qhi[1][nt], m);
            float4_ rs = MFMAH(a0, qlo[0][nt], F4Z);
            rs = MFMAH(a1, qlo[1][nt], rs);
            v0[nt] = m[0] + rs[0];
            v1[nt] = m[1] + rs[1];
        }
        pw_dec(v0, v1, 1);
        lds_barrier();
    }

    // decoder steps 1..499 (Wcomb; out hi-only side-store)
    load_dec(WS_COMB, WS_BCOMB);

    auto dec_step = [&](int CUR, int s) {
        const half8 a0 = *(const half8*)(lds + DEC_H(CUR,0,rg) + lcol*16);
        const half8 a1 = *(const half8*)(lds + DEC_H(CUR,1,rg) + lcol*16);
        float v0[4], v1[4];
        #pragma unroll
        for (int nt = 0; nt < 4; ++nt) {
            float4_ m = {bias[nt], bias[nt], bias[nt], bias[nt]};
            m = MFMAH(a0, qhi[0][nt], m);
            m = MFMAH(a1, qhi[1][nt], m);
            float4_ rs = MFMAH(a0, qlo[0][nt], F4Z);
            rs = MFMAH(a1, qlo[1][nt], rs);
            v0[nt] = m[0] + rs[0];
            v1[nt] = m[1] + rs[1];
        }
        if (ow) {   // out_{s-1} = h_s @ Wout^T + bout (hi-only); stores fly across barrier
            float4_ om = {bo, bo, bo, bo};
            om = MFMAH(a0, woh[0], om);
            om = MFMAH(a1, woh[1], om);
            out[((size_t)(row0 + 2*rg + 0)*T_SEQ + (s-1))*D_IN + ocol] = om[0];
            out[((size_t)(row0 + 2*rg + 1)*T_SEQ + (s-1))*D_IN + ocol] = om[1];
        }
        pw_dec(v0, v1, CUR ^ 1);
        lds_barrier();
    };

    int s = 1;
    for (int it = 0; it < 249; ++it) { dec_step(1, s); ++s; dec_step(0, s); ++s; }
    dec_step(1, 499);   // writes h_500 into DEC buf0

    // tail: out_499 = h_500 @ Wout^T + bout
    if (ow) {
        const half8 a0 = *(const half8*)(lds + DEC_H(0,0,rg) + lcol*16);
        const half8 a1 = *(const half8*)(lds + DEC_H(0,1,rg) + lcol*16);
        float4_ om = {bo, bo, bo, bo};
        om = MFMAH(a0, woh[0], om);
        om = MFMAH(a1, woh[1], om);
        out[((size_t)(row0 + 2*rg + 0)*T_SEQ + (T_SEQ-1))*D_IN + ocol] = om[0];
        out[((size_t)(row0 + 2*rg + 1)*T_SEQ + (T_SEQ-1))*D_IN + ocol] = om[1];
    }
}

extern "C" void kernel_launch(void* const* d_in, const int* in_sizes, int n_in,
                              void* d_out, int out_size, void* d_ws, size_t ws_size,
                              hipStream_t stream) {
    (void)n_in; (void)ws_size; (void)out_size;
    const float* x     = (const float*)d_in[0];
    const float* Wih_e = (const float*)d_in[1];
    const float* Whh_e = (const float*)d_in[2];
    const float* b_e   = (const float*)d_in[3];
    const float* Wih_d = (const float*)d_in[4];
    const float* Whh_d = (const float*)d_in[5];
    const float* b_d   = (const float*)d_in[6];
    const float* Wout  = (const float*)d_in[7];
    const float* bout  = (const float*)d_in[8];
    float* out = (float*)d_out;

    const int B = in_sizes[0] / (T_SEQ * D_IN);   // 4096

    hipLaunchKernelGGL(prep_kernel, dim3(8), dim3(512), 0, stream,
                       Wih_e, Whh_e, b_e, Wih_d, Whh_d, b_d, Wout, bout, (char*)d_ws);
    hipLaunchKernelGGL(seq2seq_main, dim3(B / ROWS), dim3(BDIM), 0, stream,
                       x, (const char*)d_ws, out);
}